// Round 4
// baseline (411.283 us; speedup 1.0000x reference)
//
#include <hip/hip_runtime.h>
#include <hip/hip_bf16.h>
#include <stdint.h>

// (B, L, QD, H, D) = (2, 2048, 1024, 16, 64)
#define BB 2
#define LL 2048
#define QDIM 1024
#define NH 16
#define HD 64

using bf16x8 = __attribute__((ext_vector_type(8))) __bf16;
using f32x4  = __attribute__((ext_vector_type(4))) float;
using u16x8  = __attribute__((ext_vector_type(8))) unsigned short;
using u32x2  = __attribute__((ext_vector_type(2))) uint32_t;

__device__ __forceinline__ unsigned short f2bf(float f) {
  uint32_t u = __builtin_bit_cast(uint32_t, f);
  u = (u + 0x7fffu + ((u >> 16) & 1u)) >> 16;   // RNE
  return (unsigned short)u;
}
__device__ __forceinline__ float bf2f(unsigned short h) {
  uint32_t u = ((uint32_t)h) << 16;
  return __builtin_bit_cast(float, u);
}

__device__ __forceinline__ void gload_lds16(const void* g, void* l) {
  __builtin_amdgcn_global_load_lds((__attribute__((address_space(1))) void*)g,
                                   (__attribute__((address_space(3))) void*)l,
                                   16, 0, 0);
}

// ---------------- fp32 -> bf16 cast ----------------
__global__ __launch_bounds__(256) void k_cast_bf16(const float* __restrict__ in,
                                                   unsigned short* __restrict__ out, int n) {
  int i = (blockIdx.x * 256 + threadIdx.x) * 8;
  if (i >= n) return;
  float4 a = *reinterpret_cast<const float4*>(in + i);
  float4 b = *reinterpret_cast<const float4*>(in + i + 4);
  u16x8 o;
  o[0] = f2bf(a.x); o[1] = f2bf(a.y); o[2] = f2bf(a.z); o[3] = f2bf(a.w);
  o[4] = f2bf(b.x); o[5] = f2bf(b.y); o[6] = f2bf(b.z); o[7] = f2bf(b.w);
  *reinterpret_cast<u16x8*>(out + i) = o;
}

// ---------------- GEMM C = A * B^T, 128x128 tile, BK=32, 4 waves ----------------
// MODE 0: bf16 C at ldc (Wq -> qk cols 0..1023)
// MODE 1: kv split: col<1024 -> qk[row*2048+1024+col] (K); col>=1024 -> vT transposed (V)
// MODE 2: f32 C + bias (proj)
template <int MODE>
__global__ __launch_bounds__(256) void k_gemm_bt(const unsigned short* __restrict__ A,
                                                 const unsigned short* __restrict__ Bw,
                                                 unsigned short* __restrict__ Cb,
                                                 float* __restrict__ Cf,
                                                 unsigned short* __restrict__ vT,
                                                 const float* __restrict__ bias,
                                                 int K, int ldc) {
  __shared__ unsigned short As[128 * 32];
  __shared__ unsigned short Bs[128 * 32];
  const int t = threadIdx.x;
  const int lane = t & 63, w = t >> 6;
  const int wm = w >> 1, wn = w & 1;
  const int g = lane >> 4, r16 = lane & 15;
  const size_t am0 = (size_t)blockIdx.x * 128;
  const size_t bn0 = (size_t)blockIdx.y * 128;

  f32x4 acc[4][4] = {};

  const int o0 = t * 16;
  const int row0 = o0 >> 6, cb0 = o0 & 63;
  const int o1 = 4096 + t * 16;
  const int row1 = o1 >> 6, cb1 = o1 & 63;

  for (int kb = 0; kb < K; kb += 32) {
    __syncthreads();
    gload_lds16(A  + (am0 + row0) * K + kb + (cb0 >> 1), (char*)As + o0);
    gload_lds16(A  + (am0 + row1) * K + kb + (cb1 >> 1), (char*)As + o1);
    gload_lds16(Bw + (bn0 + row0) * K + kb + (cb0 >> 1), (char*)Bs + o0);
    gload_lds16(Bw + (bn0 + row1) * K + kb + (cb1 >> 1), (char*)Bs + o1);
    __syncthreads();

    bf16x8 af[4], bfr[4];
#pragma unroll
    for (int i = 0; i < 4; ++i)
      af[i] = *reinterpret_cast<const bf16x8*>((const char*)As + (wm * 64 + i * 16 + r16) * 64 + g * 16);
#pragma unroll
    for (int j = 0; j < 4; ++j)
      bfr[j] = *reinterpret_cast<const bf16x8*>((const char*)Bs + (wn * 64 + j * 16 + r16) * 64 + g * 16);
#pragma unroll
    for (int i = 0; i < 4; ++i)
#pragma unroll
      for (int j = 0; j < 4; ++j)
        acc[i][j] = __builtin_amdgcn_mfma_f32_16x16x32_bf16(af[i], bfr[j], acc[i][j], 0, 0, 0);
  }

  // epilogue: C row = am0+wm*64+i*16+g*4+r, col = bn0+wn*64+j*16+r16
#pragma unroll
  for (int i = 0; i < 4; ++i)
#pragma unroll
    for (int j = 0; j < 4; ++j) {
      size_t row = am0 + wm * 64 + i * 16 + g * 4;
      int col = (int)bn0 + wn * 64 + j * 16 + r16;
      if (MODE == 2) {
#pragma unroll
        for (int r = 0; r < 4; ++r) Cf[(row + r) * ldc + col] = acc[i][j][r] + bias[col];
      } else if (MODE == 0) {
#pragma unroll
        for (int r = 0; r < 4; ++r) Cb[(row + r) * ldc + col] = f2bf(acc[i][j][r]);
      } else {  // MODE 1
        if (col < 1024) {
#pragma unroll
          for (int r = 0; r < 4; ++r) Cb[(row + r) * 2048 + 1024 + col] = f2bf(acc[i][j][r]);
        } else {
          int e = col - 1024, h = e >> 6, d = e & 63;
          int b = (int)(row >> 11), l2 = (int)(row & 2047);
          ushort4 pk;
          pk.x = f2bf(acc[i][j][0]); pk.y = f2bf(acc[i][j][1]);
          pk.z = f2bf(acc[i][j][2]); pk.w = f2bf(acc[i][j][3]);
          *reinterpret_cast<ushort4*>(vT + ((size_t)(b * 16 + h) * 64 + d) * 2048 + l2) = pk;
        }
      }
    }
}

// ---------------- per-head RMSNorm + RoPE, in place on qk (stride 2048) ----------------
// grid = B*L, 256 threads; lane pair-handles (2dp, 2dp+1); 32-lane group = one head
__global__ __launch_bounds__(256) void k_norm_rope(unsigned short* __restrict__ qkbuf,
                                                   const float* __restrict__ pe,
                                                   const float* __restrict__ qs,
                                                   const float* __restrict__ ks) {
  const int row = blockIdx.x;
  const int l = row & (LL - 1);
  const int t = threadIdx.x, w = t >> 6, lane = t & 63;
  const int hgrp = lane >> 5, dp = lane & 31;
  const size_t base = (size_t)row * 2048;
  const float4 pev = *reinterpret_cast<const float4*>(pe + ((size_t)l * 32 + dp) * 4);
  const float2 qsv = *reinterpret_cast<const float2*>(qs + dp * 2);
  const float2 ksv = *reinterpret_cast<const float2*>(ks + dp * 2);

#pragma unroll
  for (int pass = 0; pass < 4; ++pass) {
    const int isK = pass >> 1;
    const int h = w * 4 + (pass & 1) * 2 + hgrp;
    unsigned short* p = qkbuf + base + isK * 1024 + h * 64 + dp * 2;
    uint32_t v = *reinterpret_cast<uint32_t*>(p);
    float xe = bf2f((unsigned short)(v & 0xffff)), xo = bf2f((unsigned short)(v >> 16));
    float s = xe * xe + xo * xo;
#pragma unroll
    for (int mk = 1; mk < 32; mk <<= 1) s += __shfl_xor(s, mk);
    float rr = rsqrtf(s * (1.0f / 64.0f) + 1e-6f);
    float sx = isK ? ksv.x : qsv.x, sy = isK ? ksv.y : qsv.y;
    float ne = xe * rr * sx, no = xo * rr * sy;
    float oe = pev.x * ne + pev.y * no;
    float oo = pev.z * ne + pev.w * no;
    *reinterpret_cast<uint32_t*>(p) = (uint32_t)f2bf(oe) | ((uint32_t)f2bf(oo) << 16);
  }
}

// ---------------- flash attention, swapped operands, no block barriers ----------------
// grid (L/64, B*H), 4 waves; wave w: 16 q-rows. KV tile = 64 keys.
// S^T = mfma(K, Q): lane holds P^T[key=kb*16+g*4+r][q=r16]
// O^T = mfma(V^T, P^T): lane holds O^T[d=dt*16+g*4+r][q=r16]
// P round-trip via per-wave LDS row [q=r16][key], swizzle: phys = row*128 + (lb ^ ((r16&7)<<4))
__global__ __launch_bounds__(256, 4) void k_flash(const unsigned short* __restrict__ qkbuf,
                                                  const unsigned short* __restrict__ vT,
                                                  unsigned short* __restrict__ ob) {
  __shared__ unsigned short Plds[4][16][64];   // per-wave private P tile (swizzled)
  const int t = threadIdx.x, w = t >> 6, lane = t & 63;
  const int g = lane >> 4, r16 = lane & 15;
  const int bh = blockIdx.y, b = bh >> 4, h = bh & 15;
  const int l0 = blockIdx.x * 64 + w * 16;
  const size_t qkb = (size_t)b * LL * 2048;
  const unsigned short* Qp = qkbuf + qkb + (size_t)(l0 + r16) * 2048 + h * 64;
  const unsigned short* Kp = qkbuf + qkb + 1024 + h * 64;
  const unsigned short* Vp = vT + (size_t)bh * 64 * 2048;

  const bf16x8 qf0 = *reinterpret_cast<const bf16x8*>(Qp + g * 8);
  const bf16x8 qf1 = *reinterpret_cast<const bf16x8*>(Qp + 32 + g * 8);

  f32x4 oacc[4] = {};
  float m = -1e30f, lsum = 0.f;

  char* Pw = (char*)&Plds[w][0][0];
  const int swz = (r16 & 7) << 4;              // row-dependent XOR mask, bits 4..6
  const int rowb = r16 * 128;                  // 128B per q-row
  // write chunks (8B): logical byte = kb*32 + g*8 ; read chunks (16B): logical = s*64 + g*16
  const int wr0 = rowb + ((0 * 32 + g * 8) ^ swz);
  const int wr1 = rowb + ((1 * 32 + g * 8) ^ swz);
  const int wr2 = rowb + ((2 * 32 + g * 8) ^ swz);
  const int wr3 = rowb + ((3 * 32 + g * 8) ^ swz);
  const int rd0 = rowb + ((g * 16) ^ swz);
  const int rd1 = rowb + ((64 + g * 16) ^ swz);

  for (int kt = 0; kt < LL; kt += 64) {
    // ---- QK^T (swapped): 8 MFMA ----
    f32x4 s[4];
#pragma unroll
    for (int kb = 0; kb < 4; ++kb) {
      const unsigned short* kp = Kp + (size_t)(kt + kb * 16 + r16) * 2048 + g * 8;
      bf16x8 ka0 = *reinterpret_cast<const bf16x8*>(kp);
      bf16x8 ka1 = *reinterpret_cast<const bf16x8*>(kp + 32);
      f32x4 z = {};
      z = __builtin_amdgcn_mfma_f32_16x16x32_bf16(ka0, qf0, z, 0, 0, 0);
      z = __builtin_amdgcn_mfma_f32_16x16x32_bf16(ka1, qf1, z, 0, 0, 0);
      s[kb] = z;
    }
    // ---- online softmax (per-lane q = r16; keys split across g-groups) ----
    float p[16];
#pragma unroll
    for (int kb = 0; kb < 4; ++kb)
#pragma unroll
      for (int r = 0; r < 4; ++r) p[kb * 4 + r] = s[kb][r] * 0.125f;
    float tm = p[0];
#pragma unroll
    for (int i = 1; i < 16; ++i) tm = fmaxf(tm, p[i]);
    tm = fmaxf(tm, __shfl_xor(tm, 16));
    tm = fmaxf(tm, __shfl_xor(tm, 32));
    float nm = fmaxf(m, tm);
    float alpha = __expf(m - nm);
    m = nm;
    float ts = 0.f;
#pragma unroll
    for (int i = 0; i < 16; ++i) { p[i] = __expf(p[i] - nm); ts += p[i]; }
    ts += __shfl_xor(ts, 16);
    ts += __shfl_xor(ts, 32);
    lsum = lsum * alpha + ts;
#pragma unroll
    for (int dt = 0; dt < 4; ++dt) oacc[dt] *= alpha;
    // ---- P -> bf16 -> per-wave LDS (swizzled, row-local) ----
    {
      u32x2 wv;
      wv[0] = (uint32_t)f2bf(p[0])  | ((uint32_t)f2bf(p[1])  << 16);
      wv[1] = (uint32_t)f2bf(p[2])  | ((uint32_t)f2bf(p[3])  << 16);
      *reinterpret_cast<u32x2*>(Pw + wr0) = wv;
      wv[0] = (uint32_t)f2bf(p[4])  | ((uint32_t)f2bf(p[5])  << 16);
      wv[1] = (uint32_t)f2bf(p[6])  | ((uint32_t)f2bf(p[7])  << 16);
      *reinterpret_cast<u32x2*>(Pw + wr1) = wv;
      wv[0] = (uint32_t)f2bf(p[8])  | ((uint32_t)f2bf(p[9])  << 16);
      wv[1] = (uint32_t)f2bf(p[10]) | ((uint32_t)f2bf(p[11]) << 16);
      *reinterpret_cast<u32x2*>(Pw + wr2) = wv;
      wv[0] = (uint32_t)f2bf(p[12]) | ((uint32_t)f2bf(p[13]) << 16);
      wv[1] = (uint32_t)f2bf(p[14]) | ((uint32_t)f2bf(p[15]) << 16);
      *reinterpret_cast<u32x2*>(Pw + wr3) = wv;
    }
    // same-wave LDS ordering: drain writes before the dependent reads
    __asm__ __volatile__("s_waitcnt lgkmcnt(0)" ::: "memory");
    bf16x8 pb0 = *reinterpret_cast<const bf16x8*>(Pw + rd0);
    bf16x8 pb1 = *reinterpret_cast<const bf16x8*>(Pw + rd1);
    // ---- O^T += V^T * P^T : 8 MFMA, V^T frags straight from global ----
#pragma unroll
    for (int dt = 0; dt < 4; ++dt) {
      const unsigned short* vp = Vp + (size_t)(dt * 16 + r16) * 2048 + kt + g * 8;
      bf16x8 va0 = *reinterpret_cast<const bf16x8*>(vp);
      bf16x8 va1 = *reinterpret_cast<const bf16x8*>(vp + 32);
      oacc[dt] = __builtin_amdgcn_mfma_f32_16x16x32_bf16(va0, pb0, oacc[dt], 0, 0, 0);
      oacc[dt] = __builtin_amdgcn_mfma_f32_16x16x32_bf16(va1, pb1, oacc[dt], 0, 0, 0);
    }
  }

  // epilogue: lane holds O^T[d=dt*16+g*4+r][q=r16]; 4 consecutive d -> 8B store
  const float inv = 1.0f / lsum;
  const size_t orow = (size_t)(b * LL + l0 + r16) * 1024 + h * 64;
#pragma unroll
  for (int dt = 0; dt < 4; ++dt) {
    ushort4 pk;
    pk.x = f2bf(oacc[dt][0] * inv); pk.y = f2bf(oacc[dt][1] * inv);
    pk.z = f2bf(oacc[dt][2] * inv); pk.w = f2bf(oacc[dt][3] * inv);
    *reinterpret_cast<ushort4*>(ob + orow + dt * 16 + g * 4) = pk;
  }
}

// ---------------- launch ----------------
extern "C" void kernel_launch(void* const* d_in, const int* in_sizes, int n_in,
                              void* d_out, int out_size, void* d_ws, size_t ws_size,
                              hipStream_t stream) {
  const float* x     = (const float*)d_in[0];
  const float* pe    = (const float*)d_in[1];
  const float* Wq    = (const float*)d_in[2];
  const float* Wkv   = (const float*)d_in[3];
  const float* Wproj = (const float*)d_in[4];
  const float* bproj = (const float*)d_in[5];
  const float* qs    = (const float*)d_in[6];
  const float* ks    = (const float*)d_in[7];
  float* out = (float*)d_out;

  char* ws = (char*)d_ws;
  unsigned short* xb     = (unsigned short*)(ws);                        //  8MB x bf16
  unsigned short* Wqb    = (unsigned short*)(ws + 8u  * 1024 * 1024);    //  2MB
  unsigned short* Wkvb   = (unsigned short*)(ws + 10u * 1024 * 1024);    //  4MB
  unsigned short* Wprojb = (unsigned short*)(ws + 14u * 1024 * 1024);    //  2MB
  unsigned short* qk     = (unsigned short*)(ws + 16u * 1024 * 1024);    // [4096][2048] 16MB (q|k)
  unsigned short* vT     = (unsigned short*)(ws + 32u * 1024 * 1024);    // [32*64][2048] 8MB
  unsigned short* ob     = (unsigned short*)(ws + 40u * 1024 * 1024);    // [4096][1024] 8MB

  k_cast_bf16<<<4194304 / 2048, 256, 0, stream>>>(x, xb, 4194304);
  k_cast_bf16<<<1048576 / 2048, 256, 0, stream>>>(Wq, Wqb, 1048576);
  k_cast_bf16<<<2097152 / 2048, 256, 0, stream>>>(Wkv, Wkvb, 2097152);
  k_cast_bf16<<<1048576 / 2048, 256, 0, stream>>>(Wproj, Wprojb, 1048576);

  k_gemm_bt<0><<<dim3(32, 8),  256, 0, stream>>>(xb, Wqb,  qk, nullptr, nullptr, nullptr, 1024, 2048);
  k_gemm_bt<1><<<dim3(32, 16), 256, 0, stream>>>(xb, Wkvb, qk, nullptr, vT,      nullptr, 1024, 0);

  k_norm_rope<<<BB * LL, 256, 0, stream>>>(qk, pe, qs, ks);
  k_flash<<<dim3(LL / 64, BB * NH), 256, 0, stream>>>(qk, vT, ob);

  k_gemm_bt<2><<<dim3(32, 8), 256, 0, stream>>>(ob, Wprojb, nullptr, out, nullptr, bproj, 1024, 1024);
}

// Round 5
// 253.351 us; speedup vs baseline: 1.6234x; 1.6234x over previous
//
#include <hip/hip_runtime.h>
#include <hip/hip_bf16.h>
#include <stdint.h>

// (B, L, QD, H, D) = (2, 2048, 1024, 16, 64)
#define BB 2
#define LL 2048
#define QDIM 1024
#define NH 16
#define HD 64

using bf16x8 = __attribute__((ext_vector_type(8))) __bf16;
using f32x4  = __attribute__((ext_vector_type(4))) float;
using u16x8  = __attribute__((ext_vector_type(8))) unsigned short;
using u32x2  = __attribute__((ext_vector_type(2))) uint32_t;

__device__ __forceinline__ unsigned short f2bf(float f) {
  uint32_t u = __builtin_bit_cast(uint32_t, f);
  u = (u + 0x7fffu + ((u >> 16) & 1u)) >> 16;   // RNE
  return (unsigned short)u;
}
__device__ __forceinline__ float bf2f(unsigned short h) {
  uint32_t u = ((uint32_t)h) << 16;
  return __builtin_bit_cast(float, u);
}

__device__ __forceinline__ void gload_lds16(const void* g, void* l) {
  __builtin_amdgcn_global_load_lds((__attribute__((address_space(1))) void*)g,
                                   (__attribute__((address_space(3))) void*)l,
                                   16, 0, 0);
}

// ---------------- fp32 -> bf16 cast ----------------
__global__ __launch_bounds__(256) void k_cast_bf16(const float* __restrict__ in,
                                                   unsigned short* __restrict__ out, int n) {
  int i = (blockIdx.x * 256 + threadIdx.x) * 8;
  if (i >= n) return;
  float4 a = *reinterpret_cast<const float4*>(in + i);
  float4 b = *reinterpret_cast<const float4*>(in + i + 4);
  u16x8 o;
  o[0] = f2bf(a.x); o[1] = f2bf(a.y); o[2] = f2bf(a.z); o[3] = f2bf(a.w);
  o[4] = f2bf(b.x); o[5] = f2bf(b.y); o[6] = f2bf(b.z); o[7] = f2bf(b.w);
  *reinterpret_cast<u16x8*>(out + i) = o;
}

// ---------------- GEMM C = A * B^T, 128x128 tile, BK=32, 4 waves ----------------
// MODE 0: bf16 C at ldc (Wq -> qk cols 0..1023)
// MODE 1: kv split: col<1024 -> qk[row*2048+1024+col] (K); col>=1024 -> vT transposed (V)
// MODE 2: f32 C + bias (proj)
template <int MODE>
__global__ __launch_bounds__(256) void k_gemm_bt(const unsigned short* __restrict__ A,
                                                 const unsigned short* __restrict__ Bw,
                                                 unsigned short* __restrict__ Cb,
                                                 float* __restrict__ Cf,
                                                 unsigned short* __restrict__ vT,
                                                 const float* __restrict__ bias,
                                                 int K, int ldc) {
  __shared__ unsigned short As[128 * 32];
  __shared__ unsigned short Bs[128 * 32];
  const int t = threadIdx.x;
  const int lane = t & 63, w = t >> 6;
  const int wm = w >> 1, wn = w & 1;
  const int g = lane >> 4, r16 = lane & 15;
  const size_t am0 = (size_t)blockIdx.x * 128;
  const size_t bn0 = (size_t)blockIdx.y * 128;

  f32x4 acc[4][4] = {};

  const int o0 = t * 16;
  const int row0 = o0 >> 6, cb0 = o0 & 63;
  const int o1 = 4096 + t * 16;
  const int row1 = o1 >> 6, cb1 = o1 & 63;

  for (int kb = 0; kb < K; kb += 32) {
    __syncthreads();
    gload_lds16(A  + (am0 + row0) * K + kb + (cb0 >> 1), (char*)As + o0);
    gload_lds16(A  + (am0 + row1) * K + kb + (cb1 >> 1), (char*)As + o1);
    gload_lds16(Bw + (bn0 + row0) * K + kb + (cb0 >> 1), (char*)Bs + o0);
    gload_lds16(Bw + (bn0 + row1) * K + kb + (cb1 >> 1), (char*)Bs + o1);
    __syncthreads();

    bf16x8 af[4], bfr[4];
#pragma unroll
    for (int i = 0; i < 4; ++i)
      af[i] = *reinterpret_cast<const bf16x8*>((const char*)As + (wm * 64 + i * 16 + r16) * 64 + g * 16);
#pragma unroll
    for (int j = 0; j < 4; ++j)
      bfr[j] = *reinterpret_cast<const bf16x8*>((const char*)Bs + (wn * 64 + j * 16 + r16) * 64 + g * 16);
#pragma unroll
    for (int i = 0; i < 4; ++i)
#pragma unroll
      for (int j = 0; j < 4; ++j)
        acc[i][j] = __builtin_amdgcn_mfma_f32_16x16x32_bf16(af[i], bfr[j], acc[i][j], 0, 0, 0);
  }

  // epilogue: C row = am0+wm*64+i*16+g*4+r, col = bn0+wn*64+j*16+r16
#pragma unroll
  for (int i = 0; i < 4; ++i)
#pragma unroll
    for (int j = 0; j < 4; ++j) {
      size_t row = am0 + wm * 64 + i * 16 + g * 4;
      int col = (int)bn0 + wn * 64 + j * 16 + r16;
      if (MODE == 2) {
#pragma unroll
        for (int r = 0; r < 4; ++r) Cf[(row + r) * ldc + col] = acc[i][j][r] + bias[col];
      } else if (MODE == 0) {
#pragma unroll
        for (int r = 0; r < 4; ++r) Cb[(row + r) * ldc + col] = f2bf(acc[i][j][r]);
      } else {  // MODE 1
        if (col < 1024) {
#pragma unroll
          for (int r = 0; r < 4; ++r) Cb[(row + r) * 2048 + 1024 + col] = f2bf(acc[i][j][r]);
        } else {
          int e = col - 1024, h = e >> 6, d = e & 63;
          int b = (int)(row >> 11), l2 = (int)(row & 2047);
          ushort4 pk;
          pk.x = f2bf(acc[i][j][0]); pk.y = f2bf(acc[i][j][1]);
          pk.z = f2bf(acc[i][j][2]); pk.w = f2bf(acc[i][j][3]);
          *reinterpret_cast<ushort4*>(vT + ((size_t)(b * 16 + h) * 64 + d) * 2048 + l2) = pk;
        }
      }
    }
}

// ---------------- per-head RMSNorm + RoPE, in place on qk (stride 2048) ----------------
__global__ __launch_bounds__(256) void k_norm_rope(unsigned short* __restrict__ qkbuf,
                                                   const float* __restrict__ pe,
                                                   const float* __restrict__ qs,
                                                   const float* __restrict__ ks) {
  const int row = blockIdx.x;
  const int l = row & (LL - 1);
  const int t = threadIdx.x, w = t >> 6, lane = t & 63;
  const int hgrp = lane >> 5, dp = lane & 31;
  const size_t base = (size_t)row * 2048;
  const float4 pev = *reinterpret_cast<const float4*>(pe + ((size_t)l * 32 + dp) * 4);
  const float2 qsv = *reinterpret_cast<const float2*>(qs + dp * 2);
  const float2 ksv = *reinterpret_cast<const float2*>(ks + dp * 2);

#pragma unroll
  for (int pass = 0; pass < 4; ++pass) {
    const int isK = pass >> 1;
    const int h = w * 4 + (pass & 1) * 2 + hgrp;
    unsigned short* p = qkbuf + base + isK * 1024 + h * 64 + dp * 2;
    uint32_t v = *reinterpret_cast<uint32_t*>(p);
    float xe = bf2f((unsigned short)(v & 0xffff)), xo = bf2f((unsigned short)(v >> 16));
    float s = xe * xe + xo * xo;
#pragma unroll
    for (int mk = 1; mk < 32; mk <<= 1) s += __shfl_xor(s, mk);
    float rr = rsqrtf(s * (1.0f / 64.0f) + 1e-6f);
    float sx = isK ? ksv.x : qsv.x, sy = isK ? ksv.y : qsv.y;
    float ne = xe * rr * sx, no = xo * rr * sy;
    float oe = pev.x * ne + pev.y * no;
    float oo = pev.z * ne + pev.w * no;
    *reinterpret_cast<uint32_t*>(p) = (uint32_t)f2bf(oe) | ((uint32_t)f2bf(oo) << 16);
  }
}

// ---------------- flash attention: swapped operands + LDS-staged K/V (2-phase) -------
// 1D grid 1024 (XCD-swizzled), 4 waves; wave w: q-rows [lt*64+w*16, +16). KV tile = 64.
// K tile LDS [key][128B], V^T tile LDS [d][128B], both XOR-swizzled (byte ^= (row&7)<<4).
// S^T = mfma(K,Q): lane holds P^T[key][q=r16]; O^T = mfma(V^T,P^T): lane O^T[d][q=r16].
__global__ __launch_bounds__(256, 4) void k_flash(const unsigned short* __restrict__ qkbuf,
                                                  const unsigned short* __restrict__ vT,
                                                  unsigned short* __restrict__ ob) {
  __shared__ unsigned short Plds[4][16][64];     //  8KB per-wave P tiles
  __shared__ unsigned short Ktile[2][64 * 64];   // 16KB double-buffered K
  __shared__ unsigned short Vtile[2][64 * 64];   // 16KB double-buffered V^T
  const int t = threadIdx.x, w = t >> 6, lane = t & 63;
  const int g = lane >> 4, r16 = lane & 15;
  // XCD swizzle: all 32 l-tiles of one (b,h) on one XCD (1024 = 8 XCD * 128)
  const int id = blockIdx.x;
  const int bh = (id & 7) + (((id >> 3) & 3) << 3);   // bh = id%8 + 8*((id/8)%4)
  const int lt = id >> 5;                             // 0..31
  const int b = bh >> 4, h = bh & 15;
  const int l0 = lt * 64 + w * 16;
  const size_t qkb = (size_t)b * LL * 2048;
  const unsigned short* Qp = qkbuf + qkb + (size_t)(l0 + r16) * 2048 + h * 64;
  const unsigned short* Kbase = qkbuf + qkb + 1024 + h * 64;
  const unsigned short* Vbase = vT + (size_t)bh * 64 * 2048;

  const bf16x8 qf0 = *reinterpret_cast<const bf16x8*>(Qp + g * 8);
  const bf16x8 qf1 = *reinterpret_cast<const bf16x8*>(Qp + 32 + g * 8);

  f32x4 oacc[4] = {};
  float m = -1e30f, lsum = 0.f;

  // P round-trip offsets (per-wave, row-local XOR swizzle)
  char* Pw = (char*)&Plds[w][0][0];
  const int pswz = (r16 & 7) << 4;
  const int prow = r16 * 128;
  const int wr0 = prow + ((0 * 32 + g * 8) ^ pswz);
  const int wr1 = prow + ((1 * 32 + g * 8) ^ pswz);
  const int wr2 = prow + ((2 * 32 + g * 8) ^ pswz);
  const int wr3 = prow + ((3 * 32 + g * 8) ^ pswz);
  const int rd0 = prow + ((g * 16) ^ pswz);
  const int rd1 = prow + ((64 + g * 16) ^ pswz);

  // staging decomposition: 8KB tile = 2 passes of 256 thr * 16B; linear LDS dest,
  // inverse-swizzled global source (rule: same involution on source and read)
  const int so0 = t * 16, sr0 = so0 >> 7, sl0 = (so0 & 127) ^ ((sr0 & 7) << 4);
  const int so1 = 4096 + t * 16, sr1 = so1 >> 7, sl1 = (so1 & 127) ^ ((sr1 & 7) << 4);

  // prologue: stage tile 0 into buf 0
  gload_lds16(Kbase + (size_t)sr0 * 2048 + (sl0 >> 1), (char*)&Ktile[0][0] + so0);
  gload_lds16(Kbase + (size_t)sr1 * 2048 + (sl1 >> 1), (char*)&Ktile[0][0] + so1);
  gload_lds16(Vbase + (size_t)sr0 * 2048 + (sl0 >> 1), (char*)&Vtile[0][0] + so0);
  gload_lds16(Vbase + (size_t)sr1 * 2048 + (sl1 >> 1), (char*)&Vtile[0][0] + so1);
  __syncthreads();

  const int kswz = (r16 & 7) << 4;   // frag-read swizzle (row&7 == r16&7 for 16-strided rows)

  for (int kt = 0; kt < LL; kt += 64) {
    const int cur = (kt >> 6) & 1;
    // issue next tile's staging (overlaps with compute below)
    if (kt + 64 < LL) {
      const int nxt = cur ^ 1;
      gload_lds16(Kbase + (size_t)(kt + 64 + sr0) * 2048 + (sl0 >> 1), (char*)&Ktile[nxt][0] + so0);
      gload_lds16(Kbase + (size_t)(kt + 64 + sr1) * 2048 + (sl1 >> 1), (char*)&Ktile[nxt][0] + so1);
      gload_lds16(Vbase + (size_t)sr0 * 2048 + kt + 64 + (sl0 >> 1), (char*)&Vtile[nxt][0] + so0);
      gload_lds16(Vbase + (size_t)sr1 * 2048 + kt + 64 + (sl1 >> 1), (char*)&Vtile[nxt][0] + so1);
    }
    const char* Kt = (const char*)&Ktile[cur][0];
    const char* Vt = (const char*)&Vtile[cur][0];

    // ---- QK^T (swapped): 8 MFMA, K frags from LDS ----
    f32x4 s[4];
#pragma unroll
    for (int kb = 0; kb < 4; ++kb) {
      const char* kp = Kt + (kb * 16 + r16) * 128;
      bf16x8 ka0 = *reinterpret_cast<const bf16x8*>(kp + ((g * 16) ^ kswz));
      bf16x8 ka1 = *reinterpret_cast<const bf16x8*>(kp + ((64 + g * 16) ^ kswz));
      f32x4 z = {};
      z = __builtin_amdgcn_mfma_f32_16x16x32_bf16(ka0, qf0, z, 0, 0, 0);
      z = __builtin_amdgcn_mfma_f32_16x16x32_bf16(ka1, qf1, z, 0, 0, 0);
      s[kb] = z;
    }
    // ---- online softmax (per-lane q = r16) ----
    float p[16];
#pragma unroll
    for (int kb = 0; kb < 4; ++kb)
#pragma unroll
      for (int r = 0; r < 4; ++r) p[kb * 4 + r] = s[kb][r] * 0.125f;
    float tm = p[0];
#pragma unroll
    for (int i = 1; i < 16; ++i) tm = fmaxf(tm, p[i]);
    tm = fmaxf(tm, __shfl_xor(tm, 16));
    tm = fmaxf(tm, __shfl_xor(tm, 32));
    float nm = fmaxf(m, tm);
    float alpha = __expf(m - nm);
    m = nm;
    float ts = 0.f;
#pragma unroll
    for (int i = 0; i < 16; ++i) { p[i] = __expf(p[i] - nm); ts += p[i]; }
    ts += __shfl_xor(ts, 16);
    ts += __shfl_xor(ts, 32);
    lsum = lsum * alpha + ts;
#pragma unroll
    for (int dt = 0; dt < 4; ++dt) oacc[dt] *= alpha;
    // ---- P -> bf16 -> per-wave LDS (swizzled, row-local) ----
    {
      u32x2 wv;
      wv[0] = (uint32_t)f2bf(p[0])  | ((uint32_t)f2bf(p[1])  << 16);
      wv[1] = (uint32_t)f2bf(p[2])  | ((uint32_t)f2bf(p[3])  << 16);
      *reinterpret_cast<u32x2*>(Pw + wr0) = wv;
      wv[0] = (uint32_t)f2bf(p[4])  | ((uint32_t)f2bf(p[5])  << 16);
      wv[1] = (uint32_t)f2bf(p[6])  | ((uint32_t)f2bf(p[7])  << 16);
      *reinterpret_cast<u32x2*>(Pw + wr1) = wv;
      wv[0] = (uint32_t)f2bf(p[8])  | ((uint32_t)f2bf(p[9])  << 16);
      wv[1] = (uint32_t)f2bf(p[10]) | ((uint32_t)f2bf(p[11]) << 16);
      *reinterpret_cast<u32x2*>(Pw + wr2) = wv;
      wv[0] = (uint32_t)f2bf(p[12]) | ((uint32_t)f2bf(p[13]) << 16);
      wv[1] = (uint32_t)f2bf(p[14]) | ((uint32_t)f2bf(p[15]) << 16);
      *reinterpret_cast<u32x2*>(Pw + wr3) = wv;
    }
    __asm__ __volatile__("s_waitcnt lgkmcnt(0)" ::: "memory");
    bf16x8 pb0 = *reinterpret_cast<const bf16x8*>(Pw + rd0);
    bf16x8 pb1 = *reinterpret_cast<const bf16x8*>(Pw + rd1);
    // ---- O^T += V^T * P^T : 8 MFMA, V^T frags from LDS ----
#pragma unroll
    for (int dt = 0; dt < 4; ++dt) {
      const char* vp = Vt + (dt * 16 + r16) * 128;
      bf16x8 va0 = *reinterpret_cast<const bf16x8*>(vp + ((g * 16) ^ kswz));
      bf16x8 va1 = *reinterpret_cast<const bf16x8*>(vp + ((64 + g * 16) ^ kswz));
      oacc[dt] = __builtin_amdgcn_mfma_f32_16x16x32_bf16(va0, pb0, oacc[dt], 0, 0, 0);
      oacc[dt] = __builtin_amdgcn_mfma_f32_16x16x32_bf16(va1, pb1, oacc[dt], 0, 0, 0);
    }
    // next buffer staged + all waves done reading cur
    __syncthreads();
  }

  // epilogue: lane holds O^T[d=dt*16+g*4+r][q=r16]; 4 consecutive d -> 8B store
  const float inv = 1.0f / lsum;
  const size_t orow = (size_t)(b * LL + l0 + r16) * 1024 + h * 64;
#pragma unroll
  for (int dt = 0; dt < 4; ++dt) {
    ushort4 pk;
    pk.x = f2bf(oacc[dt][0] * inv); pk.y = f2bf(oacc[dt][1] * inv);
    pk.z = f2bf(oacc[dt][2] * inv); pk.w = f2bf(oacc[dt][3] * inv);
    *reinterpret_cast<ushort4*>(ob + orow + dt * 16 + g * 4) = pk;
  }
}

// ---------------- launch ----------------
extern "C" void kernel_launch(void* const* d_in, const int* in_sizes, int n_in,
                              void* d_out, int out_size, void* d_ws, size_t ws_size,
                              hipStream_t stream) {
  const float* x     = (const float*)d_in[0];
  const float* pe    = (const float*)d_in[1];
  const float* Wq    = (const float*)d_in[2];
  const float* Wkv   = (const float*)d_in[3];
  const float* Wproj = (const float*)d_in[4];
  const float* bproj = (const float*)d_in[5];
  const float* qs    = (const float*)d_in[6];
  const float* ks    = (const float*)d_in[7];
  float* out = (float*)d_out;

  char* ws = (char*)d_ws;
  unsigned short* xb     = (unsigned short*)(ws);                        //  8MB x bf16
  unsigned short* Wqb    = (unsigned short*)(ws + 8u  * 1024 * 1024);    //  2MB
  unsigned short* Wkvb   = (unsigned short*)(ws + 10u * 1024 * 1024);    //  4MB
  unsigned short* Wprojb = (unsigned short*)(ws + 14u * 1024 * 1024);    //  2MB
  unsigned short* qk     = (unsigned short*)(ws + 16u * 1024 * 1024);    // [4096][2048] 16MB (q|k)
  unsigned short* vT     = (unsigned short*)(ws + 32u * 1024 * 1024);    // [32*64][2048] 8MB
  unsigned short* ob     = (unsigned short*)(ws + 40u * 1024 * 1024);    // [4096][1024] 8MB

  k_cast_bf16<<<4194304 / 2048, 256, 0, stream>>>(x, xb, 4194304);
  k_cast_bf16<<<1048576 / 2048, 256, 0, stream>>>(Wq, Wqb, 1048576);
  k_cast_bf16<<<2097152 / 2048, 256, 0, stream>>>(Wkv, Wkvb, 2097152);
  k_cast_bf16<<<1048576 / 2048, 256, 0, stream>>>(Wproj, Wprojb, 1048576);

  k_gemm_bt<0><<<dim3(32, 8),  256, 0, stream>>>(xb, Wqb,  qk, nullptr, nullptr, nullptr, 1024, 2048);
  k_gemm_bt<1><<<dim3(32, 16), 256, 0, stream>>>(xb, Wkvb, qk, nullptr, vT,      nullptr, 1024, 0);

  k_norm_rope<<<BB * LL, 256, 0, stream>>>(qk, pe, qs, ks);
  k_flash<<<1024, 256, 0, stream>>>(qk, vT, ob);

  k_gemm_bt<2><<<dim3(32, 8), 256, 0, stream>>>(ob, Wprojb, nullptr, out, nullptr, bproj, 1024, 1024);
}

// Round 6
// 227.455 us; speedup vs baseline: 1.8082x; 1.1138x over previous
//
#include <hip/hip_runtime.h>
#include <hip/hip_bf16.h>
#include <stdint.h>

// (B, L, QD, H, D) = (2, 2048, 1024, 16, 64)
#define BB 2
#define LL 2048
#define QDIM 1024
#define NH 16
#define HD 64

using bf16x8 = __attribute__((ext_vector_type(8))) __bf16;
using bf16x2 = __attribute__((ext_vector_type(2))) __bf16;
using bf16x4 = __attribute__((ext_vector_type(4))) __bf16;
using f32x4  = __attribute__((ext_vector_type(4))) float;
using u16x8  = __attribute__((ext_vector_type(8))) unsigned short;
using u32x2  = __attribute__((ext_vector_type(2))) uint32_t;

__device__ __forceinline__ unsigned short f2bf(float f) {
  return __builtin_bit_cast(unsigned short, (__bf16)f);   // HW v_cvt (RNE)
}
__device__ __forceinline__ float bf2f(unsigned short h) {
  uint32_t u = ((uint32_t)h) << 16;
  return __builtin_bit_cast(float, u);
}
__device__ __forceinline__ uint32_t pkbf2(float a, float b) {
  bf16x2 v = { (__bf16)a, (__bf16)b };                    // invites v_cvt_pk_bf16_f32
  return __builtin_bit_cast(uint32_t, v);
}

__device__ __forceinline__ void gload_lds16(const void* g, void* l) {
  __builtin_amdgcn_global_load_lds((__attribute__((address_space(1))) void*)g,
                                   (__attribute__((address_space(3))) void*)l,
                                   16, 0, 0);
}

// ---------------- fp32 -> bf16 cast ----------------
__global__ __launch_bounds__(256) void k_cast_bf16(const float* __restrict__ in,
                                                   unsigned short* __restrict__ out, int n) {
  int i = (blockIdx.x * 256 + threadIdx.x) * 8;
  if (i >= n) return;
  float4 a = *reinterpret_cast<const float4*>(in + i);
  float4 b = *reinterpret_cast<const float4*>(in + i + 4);
  u16x8 o;
  o[0] = f2bf(a.x); o[1] = f2bf(a.y); o[2] = f2bf(a.z); o[3] = f2bf(a.w);
  o[4] = f2bf(b.x); o[5] = f2bf(b.y); o[6] = f2bf(b.z); o[7] = f2bf(b.w);
  *reinterpret_cast<u16x8*>(out + i) = o;
}

// ---------------- merged QKV GEMM: C = xb * Wall^T, 128x128 tile, BK=32 ----------------
// Wall rows: [0,1024)=Wq, [1024,2048)=Wk, [2048,3072)=Wv
// cols<2048 -> qk[row*2048+col] bf16 ; cols>=2048 -> vT[(bh*64+d)*2048 + l] transposed
__global__ __launch_bounds__(256) void k_gemm_qkv(const unsigned short* __restrict__ A,
                                                  const unsigned short* __restrict__ Bw,
                                                  unsigned short* __restrict__ qk,
                                                  unsigned short* __restrict__ vT) {
  __shared__ unsigned short As[128 * 32];
  __shared__ unsigned short Bs[128 * 32];
  const int t = threadIdx.x;
  const int lane = t & 63, w = t >> 6;
  const int wm = w >> 1, wn = w & 1;
  const int g = lane >> 4, r16 = lane & 15;
  const size_t am0 = (size_t)blockIdx.x * 128;
  const size_t bn0 = (size_t)blockIdx.y * 128;
  const int K = 1024;

  f32x4 acc[4][4] = {};

  const int o0 = t * 16, row0 = o0 >> 6, cb0 = o0 & 63;
  const int o1 = 4096 + t * 16, row1 = o1 >> 6, cb1 = o1 & 63;

  for (int kb = 0; kb < K; kb += 32) {
    __syncthreads();
    gload_lds16(A  + (am0 + row0) * K + kb + (cb0 >> 1), (char*)As + o0);
    gload_lds16(A  + (am0 + row1) * K + kb + (cb1 >> 1), (char*)As + o1);
    gload_lds16(Bw + (bn0 + row0) * K + kb + (cb0 >> 1), (char*)Bs + o0);
    gload_lds16(Bw + (bn0 + row1) * K + kb + (cb1 >> 1), (char*)Bs + o1);
    __syncthreads();

    bf16x8 af[4], bfr[4];
#pragma unroll
    for (int i = 0; i < 4; ++i)
      af[i] = *reinterpret_cast<const bf16x8*>((const char*)As + (wm * 64 + i * 16 + r16) * 64 + g * 16);
#pragma unroll
    for (int j = 0; j < 4; ++j)
      bfr[j] = *reinterpret_cast<const bf16x8*>((const char*)Bs + (wn * 64 + j * 16 + r16) * 64 + g * 16);
#pragma unroll
    for (int i = 0; i < 4; ++i)
#pragma unroll
      for (int j = 0; j < 4; ++j)
        acc[i][j] = __builtin_amdgcn_mfma_f32_16x16x32_bf16(af[i], bfr[j], acc[i][j], 0, 0, 0);
  }

#pragma unroll
  for (int i = 0; i < 4; ++i)
#pragma unroll
    for (int j = 0; j < 4; ++j) {
      size_t row = am0 + wm * 64 + i * 16 + g * 4;
      int col = (int)bn0 + wn * 64 + j * 16 + r16;
      if (col < 2048) {
#pragma unroll
        for (int r = 0; r < 4; ++r) qk[(row + r) * 2048 + col] = f2bf(acc[i][j][r]);
      } else {
        int e = col - 2048, h = e >> 6, d = e & 63;
        int b = (int)(row >> 11), l2 = (int)(row & 2047);
        ushort4 pk;
        pk.x = f2bf(acc[i][j][0]); pk.y = f2bf(acc[i][j][1]);
        pk.z = f2bf(acc[i][j][2]); pk.w = f2bf(acc[i][j][3]);
        *reinterpret_cast<ushort4*>(vT + ((size_t)(b * 16 + h) * 64 + d) * 2048 + l2) = pk;
      }
    }
}

// ---------------- proj GEMM: out = ob * Wproj^T + bias, 64x128 tile ----------------
__global__ __launch_bounds__(256) void k_gemm_proj(const unsigned short* __restrict__ A,
                                                   const unsigned short* __restrict__ Bw,
                                                   float* __restrict__ Cf,
                                                   const float* __restrict__ bias) {
  __shared__ unsigned short As[64 * 32];    // 4KB
  __shared__ unsigned short Bs[128 * 32];   // 8KB
  const int t = threadIdx.x;
  const int lane = t & 63, w = t >> 6;
  const int wm = w >> 1, wn = w & 1;        // waves 2x2: rows wm*32, cols wn*64
  const int g = lane >> 4, r16 = lane & 15;
  const size_t am0 = (size_t)blockIdx.x * 64;
  const size_t bn0 = (size_t)blockIdx.y * 128;
  const int K = 1024;

  f32x4 acc[2][4] = {};

  const int oa = t * 16, rowa = oa >> 6, cba = oa & 63;             // As: 1 pass
  const int ob0 = t * 16, rowb0 = ob0 >> 6, cbb0 = ob0 & 63;        // Bs: 2 passes
  const int ob1 = 4096 + t * 16, rowb1 = ob1 >> 6, cbb1 = ob1 & 63;

  for (int kb = 0; kb < K; kb += 32) {
    __syncthreads();
    gload_lds16(A  + (am0 + rowa)  * K + kb + (cba  >> 1), (char*)As + oa);
    gload_lds16(Bw + (bn0 + rowb0) * K + kb + (cbb0 >> 1), (char*)Bs + ob0);
    gload_lds16(Bw + (bn0 + rowb1) * K + kb + (cbb1 >> 1), (char*)Bs + ob1);
    __syncthreads();

    bf16x8 af[2], bfr[4];
#pragma unroll
    for (int i = 0; i < 2; ++i)
      af[i] = *reinterpret_cast<const bf16x8*>((const char*)As + (wm * 32 + i * 16 + r16) * 64 + g * 16);
#pragma unroll
    for (int j = 0; j < 4; ++j)
      bfr[j] = *reinterpret_cast<const bf16x8*>((const char*)Bs + (wn * 64 + j * 16 + r16) * 64 + g * 16);
#pragma unroll
    for (int i = 0; i < 2; ++i)
#pragma unroll
      for (int j = 0; j < 4; ++j)
        acc[i][j] = __builtin_amdgcn_mfma_f32_16x16x32_bf16(af[i], bfr[j], acc[i][j], 0, 0, 0);
  }

#pragma unroll
  for (int i = 0; i < 2; ++i)
#pragma unroll
    for (int j = 0; j < 4; ++j) {
      size_t row = am0 + wm * 32 + i * 16 + g * 4;
      int col = (int)bn0 + wn * 64 + j * 16 + r16;
#pragma unroll
      for (int r = 0; r < 4; ++r) Cf[(row + r) * 1024 + col] = acc[i][j][r] + bias[col];
    }
}

// ---------------- per-head RMSNorm + RoPE, in place on qk (stride 2048) ----------------
// q additionally pre-scaled by 0.125*log2(e) so flash softmax runs in exp2 domain.
__global__ __launch_bounds__(256) void k_norm_rope(unsigned short* __restrict__ qkbuf,
                                                   const float* __restrict__ pe,
                                                   const float* __restrict__ qs,
                                                   const float* __restrict__ ks) {
  const float S2 = 0.125f * 1.44269504f;   // 1/sqrt(64) * log2(e)
  const int row = blockIdx.x;
  const int l = row & (LL - 1);
  const int t = threadIdx.x, w = t >> 6, lane = t & 63;
  const int hgrp = lane >> 5, dp = lane & 31;
  const size_t base = (size_t)row * 2048;
  const float4 pev = *reinterpret_cast<const float4*>(pe + ((size_t)l * 32 + dp) * 4);
  const float2 qsv0 = *reinterpret_cast<const float2*>(qs + dp * 2);
  const float2 ksv = *reinterpret_cast<const float2*>(ks + dp * 2);
  const float2 qsv = { qsv0.x * S2, qsv0.y * S2 };

#pragma unroll
  for (int pass = 0; pass < 4; ++pass) {
    const int isK = pass >> 1;
    const int h = w * 4 + (pass & 1) * 2 + hgrp;
    unsigned short* p = qkbuf + base + isK * 1024 + h * 64 + dp * 2;
    uint32_t v = *reinterpret_cast<uint32_t*>(p);
    float xe = bf2f((unsigned short)(v & 0xffff)), xo = bf2f((unsigned short)(v >> 16));
    float s = xe * xe + xo * xo;
#pragma unroll
    for (int mk = 1; mk < 32; mk <<= 1) s += __shfl_xor(s, mk);
    float rr = rsqrtf(s * (1.0f / 64.0f) + 1e-6f);
    float sx = isK ? ksv.x : qsv.x, sy = isK ? ksv.y : qsv.y;
    float ne = xe * rr * sx, no = xo * rr * sy;
    float oe = pev.x * ne + pev.y * no;
    float oo = pev.z * ne + pev.w * no;
    *reinterpret_cast<uint32_t*>(p) = (uint32_t)f2bf(oe) | ((uint32_t)f2bf(oo) << 16);
  }
}

// ---------------- flash attention: swapped operands + LDS K/V 2-phase + exp2/defer-max ----
__global__ __launch_bounds__(256, 4) void k_flash(const unsigned short* __restrict__ qkbuf,
                                                  const unsigned short* __restrict__ vT,
                                                  unsigned short* __restrict__ ob) {
  __shared__ unsigned short Plds[4][16][64];     //  8KB per-wave P tiles
  __shared__ unsigned short Ktile[2][64 * 64];   // 16KB double-buffered K
  __shared__ unsigned short Vtile[2][64 * 64];   // 16KB double-buffered V^T
  const int t = threadIdx.x, w = t >> 6, lane = t & 63;
  const int g = lane >> 4, r16 = lane & 15;
  // XCD swizzle: all 32 l-tiles of one (b,h) on one XCD (1024 = 8 XCD * 128)
  const int id = blockIdx.x;
  const int bh = (id & 7) + (((id >> 3) & 3) << 3);
  const int lt = id >> 5;
  const int b = bh >> 4, h = bh & 15;
  const int l0 = lt * 64 + w * 16;
  const size_t qkb = (size_t)b * LL * 2048;
  const unsigned short* Qp = qkbuf + qkb + (size_t)(l0 + r16) * 2048 + h * 64;
  const unsigned short* Kbase = qkbuf + qkb + 1024 + h * 64;
  const unsigned short* Vbase = vT + (size_t)bh * 64 * 2048;

  const bf16x8 qf0 = *reinterpret_cast<const bf16x8*>(Qp + g * 8);
  const bf16x8 qf1 = *reinterpret_cast<const bf16x8*>(Qp + 32 + g * 8);

  f32x4 oacc[4] = {};
  float m = -1e30f, lsum = 0.f;

  char* Pw = (char*)&Plds[w][0][0];
  const int pswz = (r16 & 7) << 4;
  const int prow = r16 * 128;
  const int wr0 = prow + ((0 * 32 + g * 8) ^ pswz);
  const int wr1 = prow + ((1 * 32 + g * 8) ^ pswz);
  const int wr2 = prow + ((2 * 32 + g * 8) ^ pswz);
  const int wr3 = prow + ((3 * 32 + g * 8) ^ pswz);
  const int rd0 = prow + ((g * 16) ^ pswz);
  const int rd1 = prow + ((64 + g * 16) ^ pswz);

  const int so0 = t * 16, sr0 = so0 >> 7, sl0 = (so0 & 127) ^ ((sr0 & 7) << 4);
  const int so1 = 4096 + t * 16, sr1 = so1 >> 7, sl1 = (so1 & 127) ^ ((sr1 & 7) << 4);

  gload_lds16(Kbase + (size_t)sr0 * 2048 + (sl0 >> 1), (char*)&Ktile[0][0] + so0);
  gload_lds16(Kbase + (size_t)sr1 * 2048 + (sl1 >> 1), (char*)&Ktile[0][0] + so1);
  gload_lds16(Vbase + (size_t)sr0 * 2048 + (sl0 >> 1), (char*)&Vtile[0][0] + so0);
  gload_lds16(Vbase + (size_t)sr1 * 2048 + (sl1 >> 1), (char*)&Vtile[0][0] + so1);
  __syncthreads();

  const int kswz = (r16 & 7) << 4;

  for (int kt = 0; kt < LL; kt += 64) {
    const int cur = (kt >> 6) & 1;
    if (kt + 64 < LL) {
      const int nxt = cur ^ 1;
      gload_lds16(Kbase + (size_t)(kt + 64 + sr0) * 2048 + (sl0 >> 1), (char*)&Ktile[nxt][0] + so0);
      gload_lds16(Kbase + (size_t)(kt + 64 + sr1) * 2048 + (sl1 >> 1), (char*)&Ktile[nxt][0] + so1);
      gload_lds16(Vbase + (size_t)sr0 * 2048 + kt + 64 + (sl0 >> 1), (char*)&Vtile[nxt][0] + so0);
      gload_lds16(Vbase + (size_t)sr1 * 2048 + kt + 64 + (sl1 >> 1), (char*)&Vtile[nxt][0] + so1);
    }
    const char* Kt = (const char*)&Ktile[cur][0];
    const char* Vt = (const char*)&Vtile[cur][0];

    // ---- QK^T (swapped): 8 MFMA; scores already in log2 domain (q pre-scaled) ----
    f32x4 s[4];
#pragma unroll
    for (int kb = 0; kb < 4; ++kb) {
      const char* kp = Kt + (kb * 16 + r16) * 128;
      bf16x8 ka0 = *reinterpret_cast<const bf16x8*>(kp + ((g * 16) ^ kswz));
      bf16x8 ka1 = *reinterpret_cast<const bf16x8*>(kp + ((64 + g * 16) ^ kswz));
      f32x4 z = {};
      z = __builtin_amdgcn_mfma_f32_16x16x32_bf16(ka0, qf0, z, 0, 0, 0);
      z = __builtin_amdgcn_mfma_f32_16x16x32_bf16(ka1, qf1, z, 0, 0, 0);
      s[kb] = z;
    }
    // ---- online softmax (exp2 domain, defer-max) ----
    float p[16];
#pragma unroll
    for (int kb = 0; kb < 4; ++kb)
#pragma unroll
      for (int r = 0; r < 4; ++r) p[kb * 4 + r] = s[kb][r];
    float tm = p[0];
#pragma unroll
    for (int i = 1; i < 16; ++i) tm = fmaxf(tm, p[i]);
    tm = fmaxf(tm, __shfl_xor(tm, 16));
    tm = fmaxf(tm, __shfl_xor(tm, 32));
    if (!__all(tm <= m + 11.0f)) {           // T13 defer-max (log2 domain)
      float nm = fmaxf(m, tm);
      float alpha = __builtin_exp2f(m - nm);
      lsum *= alpha;
#pragma unroll
      for (int dt = 0; dt < 4; ++dt) oacc[dt] *= alpha;
      m = nm;
    }
    float ts = 0.f;
#pragma unroll
    for (int i = 0; i < 16; ++i) { p[i] = __builtin_exp2f(p[i] - m); ts += p[i]; }
    ts += __shfl_xor(ts, 16);
    ts += __shfl_xor(ts, 32);
    lsum += ts;
    // ---- P -> bf16 -> per-wave LDS (swizzled, row-local) ----
    {
      u32x2 wv;
      wv[0] = pkbf2(p[0],  p[1]);  wv[1] = pkbf2(p[2],  p[3]);
      *reinterpret_cast<u32x2*>(Pw + wr0) = wv;
      wv[0] = pkbf2(p[4],  p[5]);  wv[1] = pkbf2(p[6],  p[7]);
      *reinterpret_cast<u32x2*>(Pw + wr1) = wv;
      wv[0] = pkbf2(p[8],  p[9]);  wv[1] = pkbf2(p[10], p[11]);
      *reinterpret_cast<u32x2*>(Pw + wr2) = wv;
      wv[0] = pkbf2(p[12], p[13]); wv[1] = pkbf2(p[14], p[15]);
      *reinterpret_cast<u32x2*>(Pw + wr3) = wv;
    }
    __asm__ __volatile__("s_waitcnt lgkmcnt(0)" ::: "memory");
    bf16x8 pb0 = *reinterpret_cast<const bf16x8*>(Pw + rd0);
    bf16x8 pb1 = *reinterpret_cast<const bf16x8*>(Pw + rd1);
    // ---- O^T += V^T * P^T ----
#pragma unroll
    for (int dt = 0; dt < 4; ++dt) {
      const char* vp = Vt + (dt * 16 + r16) * 128;
      bf16x8 va0 = *reinterpret_cast<const bf16x8*>(vp + ((g * 16) ^ kswz));
      bf16x8 va1 = *reinterpret_cast<const bf16x8*>(vp + ((64 + g * 16) ^ kswz));
      oacc[dt] = __builtin_amdgcn_mfma_f32_16x16x32_bf16(va0, pb0, oacc[dt], 0, 0, 0);
      oacc[dt] = __builtin_amdgcn_mfma_f32_16x16x32_bf16(va1, pb1, oacc[dt], 0, 0, 0);
    }
    __syncthreads();
  }

  const float inv = 1.0f / lsum;
  const size_t orow = (size_t)(b * LL + l0 + r16) * 1024 + h * 64;
#pragma unroll
  for (int dt = 0; dt < 4; ++dt) {
    ushort4 pk;
    pk.x = f2bf(oacc[dt][0] * inv); pk.y = f2bf(oacc[dt][1] * inv);
    pk.z = f2bf(oacc[dt][2] * inv); pk.w = f2bf(oacc[dt][3] * inv);
    *reinterpret_cast<ushort4*>(ob + orow + dt * 16 + g * 4) = pk;
  }
}

// ---------------- launch ----------------
extern "C" void kernel_launch(void* const* d_in, const int* in_sizes, int n_in,
                              void* d_out, int out_size, void* d_ws, size_t ws_size,
                              hipStream_t stream) {
  const float* x     = (const float*)d_in[0];
  const float* pe    = (const float*)d_in[1];
  const float* Wq    = (const float*)d_in[2];
  const float* Wkv   = (const float*)d_in[3];
  const float* Wproj = (const float*)d_in[4];
  const float* bproj = (const float*)d_in[5];
  const float* qs    = (const float*)d_in[6];
  const float* ks    = (const float*)d_in[7];
  float* out = (float*)d_out;

  char* ws = (char*)d_ws;
  unsigned short* xb     = (unsigned short*)(ws);                        //  8MB x bf16
  unsigned short* Wall   = (unsigned short*)(ws + 8u  * 1024 * 1024);    //  6MB [Wq;Wkv] bf16
  unsigned short* Wprojb = (unsigned short*)(ws + 14u * 1024 * 1024);    //  2MB
  unsigned short* qk     = (unsigned short*)(ws + 16u * 1024 * 1024);    // [4096][2048] 16MB (q|k)
  unsigned short* vT     = (unsigned short*)(ws + 32u * 1024 * 1024);    // [32*64][2048] 8MB
  unsigned short* ob     = (unsigned short*)(ws + 40u * 1024 * 1024);    // [4096][1024] 8MB

  k_cast_bf16<<<4194304 / 2048, 256, 0, stream>>>(x, xb, 4194304);
  k_cast_bf16<<<1048576 / 2048, 256, 0, stream>>>(Wq, Wall, 1048576);
  k_cast_bf16<<<2097152 / 2048, 256, 0, stream>>>(Wkv, Wall + 1048576, 2097152);
  k_cast_bf16<<<1048576 / 2048, 256, 0, stream>>>(Wproj, Wprojb, 1048576);

  k_gemm_qkv<<<dim3(32, 24), 256, 0, stream>>>(xb, Wall, qk, vT);

  k_norm_rope<<<BB * LL, 256, 0, stream>>>(qk, pe, qs, ks);
  k_flash<<<1024, 256, 0, stream>>>(qk, vT, ob);

  k_gemm_proj<<<dim3(64, 8), 256, 0, stream>>>(ob, Wprojb, out, bproj);
}